// Round 1
// baseline (102.405 us; speedup 1.0000x reference)
//
#include <hip/hip_runtime.h>
#include <hip/hip_bf16.h>
#include <float.h>

// Problem constants (fixed by setup_inputs)
constexpr int B = 8, N = 4096, M = 4096, E = 12288;
constexpr int BLOCK = 256;
constexpr int VEC = 8;                  // query points per thread
constexpr int QPB = BLOCK * VEC;        // 2048 queries per block
constexpr int QT = N / QPB;             // 2 query tiles
constexpr int RCH = 256;                // ref-chunk size (points staged in LDS)
constexpr int NRC = M / RCH;            // 16 ref chunks
constexpr int BLK_PER_DIR = B * QT * NRC; // 256 blocks per direction

// Workspace layout (d_ws):
//   [0 .. 2*B*N)   : uint min buffers (dir0: minP1[B*N], dir1: minP2[B*M])
//   [2*B*N .. +4)  : float acc[4] = {sum_sqrt_total, unused, edgeSum, edgeSumSq}

__global__ void init_ws(unsigned* __restrict__ minbuf, float* __restrict__ acc) {
    int i = blockIdx.x * blockDim.x + threadIdx.x;
    const int total = 2 * B * N;
    for (; i < total; i += gridDim.x * blockDim.x) minbuf[i] = 0xFFFFFFFFu;
    if (blockIdx.x == 0 && threadIdx.x < 4) acc[threadIdx.x] = 0.0f;
}

__global__ __launch_bounds__(BLOCK) void chamfer_min_kernel(
    const float* __restrict__ pred, const float* __restrict__ gt,
    unsigned* __restrict__ minAll) {
    const int bid = blockIdx.x;
    const int dir = bid >> 8;                 // 0: query=pred/ref=gt, 1: swapped
    const int r   = bid & (BLK_PER_DIR - 1);
    const int b   = r >> 5;                   // / (QT*NRC) = 32
    const int rem = r & 31;
    const int qt  = rem >> 4;
    const int rc  = rem & 15;

    const float* __restrict__ q   = dir ? gt   : pred;
    const float* __restrict__ ref = dir ? pred : gt;
    unsigned* __restrict__ minOut = minAll + dir * (B * N);

    const int t = threadIdx.x;
    const int qbase = qt * QPB;

    // Load this thread's VEC query points into registers
    float qx[VEC], qy[VEC], qz[VEC], h1[VEC];
#pragma unroll
    for (int i = 0; i < VEC; i++) {
        const int n = qbase + t + i * BLOCK;
        const float* p = q + ((size_t)b * N + n) * 3;
        qx[i] = p[0]; qy[i] = p[1]; qz[i] = p[2];
        h1[i] = 0.5f * (qx[i] * qx[i] + qy[i] * qy[i] + qz[i] * qz[i]);
    }

    // Stage ref chunk into LDS as float4 {x,y,z, 0.5*|p|^2}
    __shared__ float4 tile[RCH];
    {
        const float* rp = ref + ((size_t)b * M + rc * RCH + t) * 3;
        float x = rp[0], y = rp[1], z = rp[2];
        tile[t] = make_float4(x, y, z, 0.5f * (x * x + y * y + z * z));
    }
    __syncthreads();

    float mins[VEC];
#pragma unroll
    for (int i = 0; i < VEC; i++) mins[i] = FLT_MAX;

#pragma unroll 4
    for (int m = 0; m < RCH; m++) {
        const float4 p = tile[m];   // broadcast read (all lanes same addr)
#pragma unroll
        for (int i = 0; i < VEC; i++) {
            // half_d2 = 0.5*|q|^2 + 0.5*|p|^2 - q.p   (5 VALU ops incl. min)
            float d = h1[i] + p.w;
            d = fmaf(-qx[i], p.x, d);
            d = fmaf(-qy[i], p.y, d);
            d = fmaf(-qz[i], p.z, d);
            mins[i] = fminf(mins[i], d);
        }
    }

#pragma unroll
    for (int i = 0; i < VEC; i++) {
        const int n = qbase + t + i * BLOCK;
        // clamp at 0 => non-negative float => uint order == float order
        const unsigned u = __float_as_uint(fmaxf(mins[i], 0.0f));
        atomicMin(minOut + (size_t)b * N + n, u);
    }
}

__global__ void reduce_chamfer(const unsigned* __restrict__ minAll,
                               float* __restrict__ acc) {
    int i = blockIdx.x * blockDim.x + threadIdx.x;
    float s = 0.0f;
    const int total = 2 * B * N;
    for (; i < total; i += gridDim.x * blockDim.x) {
        const float h = __uint_as_float(minAll[i]);   // half-d2, >= 0
        s += sqrtf(fmaxf(2.0f * h, 0.0f));
    }
#pragma unroll
    for (int o = 32; o > 0; o >>= 1) s += __shfl_down(s, o, 64);
    __shared__ float wsum[4];
    const int wave = threadIdx.x >> 6, lane = threadIdx.x & 63;
    if (lane == 0) wsum[wave] = s;
    __syncthreads();
    if (threadIdx.x == 0) {
        float tot = 0.0f;
        for (int w = 0; w < (int)(blockDim.x >> 6); w++) tot += wsum[w];
        atomicAdd(&acc[0], tot);
    }
}

__global__ void edge_kernel(const float* __restrict__ pred,
                            const int* __restrict__ edges,
                            float* __restrict__ acc) {
    const int j = blockIdx.x * blockDim.x + threadIdx.x;
    float L = 0.0f, L2 = 0.0f;
    if (j < B * E) {
        const int b = j / E, e = j - b * E;
        const int i0 = edges[2 * e], i1 = edges[2 * e + 1];
        const float* p0 = pred + ((size_t)b * N + i0) * 3;
        const float* p1 = pred + ((size_t)b * N + i1) * 3;
        const float dx = p0[0] - p1[0];
        const float dy = p0[1] - p1[1];
        const float dz = p0[2] - p1[2];
        L  = sqrtf(dx * dx + dy * dy + dz * dz);
        L2 = L * L;
    }
#pragma unroll
    for (int o = 32; o > 0; o >>= 1) {
        L  += __shfl_down(L, o, 64);
        L2 += __shfl_down(L2, o, 64);
    }
    __shared__ float w1[4], w2[4];
    const int wave = threadIdx.x >> 6, lane = threadIdx.x & 63;
    if (lane == 0) { w1[wave] = L; w2[wave] = L2; }
    __syncthreads();
    if (threadIdx.x == 0) {
        float a = 0.0f, c = 0.0f;
        for (int w = 0; w < 4; w++) { a += w1[w]; c += w2[w]; }
        atomicAdd(&acc[2], a);
        atomicAdd(&acc[3], c);
    }
}

__global__ void final_kernel(const float* __restrict__ acc,
                             float* __restrict__ out) {
    if (threadIdx.x == 0 && blockIdx.x == 0) {
        const float cd = acc[0] / 32768.0f;   // S1/(B*N) + S2/(B*M), N==M
        const float K = (float)(B * E);       // 98304
        const float var = (acc[3] - acc[2] * acc[2] / K) / (K - 1.0f);
        out[0] = cd + 0.1f * var;
    }
}

extern "C" void kernel_launch(void* const* d_in, const int* in_sizes, int n_in,
                              void* d_out, int out_size, void* d_ws, size_t ws_size,
                              hipStream_t stream) {
    const float* pred  = (const float*)d_in[0];
    const float* gt    = (const float*)d_in[1];
    const int*   edges = (const int*)d_in[2];
    float* out = (float*)d_out;

    unsigned* minAll = (unsigned*)d_ws;
    float*    acc    = (float*)d_ws + 2 * B * N;

    init_ws<<<64, 256, 0, stream>>>(minAll, acc);
    chamfer_min_kernel<<<2 * BLK_PER_DIR, BLOCK, 0, stream>>>(pred, gt, minAll);
    edge_kernel<<<(B * E + BLOCK - 1) / BLOCK, BLOCK, 0, stream>>>(pred, edges, acc);
    reduce_chamfer<<<128, 256, 0, stream>>>(minAll, acc);
    final_kernel<<<1, 64, 0, stream>>>(acc, out);
}